// Round 2
// baseline (1000.232 us; speedup 1.0000x reference)
//
#include <hip/hip_runtime.h>
#include <hip/hip_bf16.h>
#include <stdint.h>

#define M_DIM 8192
#define K_DIM 4096
#define N_DIM 11008

typedef __attribute__((ext_vector_type(8))) short bf16x8;
typedef __attribute__((ext_vector_type(4))) float f32x4;
typedef __attribute__((ext_vector_type(4))) unsigned int uint4v;

__device__ __forceinline__ unsigned short f2bf(float f) {
    __hip_bfloat16 h = __float2bfloat16(f);
    return __builtin_bit_cast(unsigned short, h);
}

__device__ __forceinline__ void gload_lds16(const unsigned short* g, unsigned short* l) {
    __builtin_amdgcn_global_load_lds(
        (const __attribute__((address_space(1))) void*)g,
        (__attribute__((address_space(3))) void*)l,
        16, 0, 0);
}

// ---------------------------------------------------------------------------
// Kernel 1: fused column-gather + fp32->bf16 convert for a chunk of M rows.
// xg[m][k] = bf16(x[m][ci[k]]).  x points at the chunk's first row.
// ---------------------------------------------------------------------------
__global__ void permute_x_kernel(const float* __restrict__ x,
                                 const int* __restrict__ ci,
                                 unsigned short* __restrict__ xg) {
    int idx = blockIdx.x * 256 + threadIdx.x;
    int64_t base = (int64_t)idx * 4;
    int m = (int)(base >> 12);        // K=4096
    int k = (int)(base & 4095);
    const float* xrow = x + ((int64_t)m << 12);
    int4 c4 = *reinterpret_cast<const int4*>(ci + k);
    ushort4 o;
    o.x = f2bf(xrow[c4.x]);
    o.y = f2bf(xrow[c4.y]);
    o.z = f2bf(xrow[c4.z]);
    o.w = f2bf(xrow[c4.w]);
    *reinterpret_cast<ushort4*>(xg + base) = o;
}

// ---------------------------------------------------------------------------
// Kernel 2: int4 unpack + per-group scale + transpose to wT[N][K] bf16.
// Tile 64(k) x 64(n) via LDS. packed row r holds k=2r (low nibble), k=2r+1
// (high nibble). A 64-k tile never crosses a 128-group boundary.
// ---------------------------------------------------------------------------
__global__ void dequant_w_kernel(const int* __restrict__ wp,
                                 const float* __restrict__ scales,
                                 unsigned short* __restrict__ wT) {
    __shared__ unsigned short tile[64][65];
    int n0 = blockIdx.x * 64;
    int k0 = blockIdx.y * 64;
    int g = k0 >> 7;
    int t = threadIdx.x;
    int col = t & 63;
    int r0 = t >> 6;
    float s = scales[(int64_t)g * N_DIM + n0 + col];
    int pr0 = k0 >> 1;
#pragma unroll
    for (int i = 0; i < 8; ++i) {
        int row = r0 + i * 4;                    // packed row within tile, 0..31
        int p = wp[(int64_t)(pr0 + row) * N_DIM + n0 + col];
        tile[2 * row][col]     = f2bf((float)((p & 15) - 8) * s);
        tile[2 * row + 1][col] = f2bf((float)(((p >> 4) & 15) - 8) * s);
    }
    __syncthreads();
    int nl = t >> 2;
    int kk0 = (t & 3) << 4;
    unsigned short vals[16];
#pragma unroll
    for (int j = 0; j < 16; ++j) vals[j] = tile[kk0 + j][nl];
    uint4v* dst = reinterpret_cast<uint4v*>(wT + (int64_t)(n0 + nl) * K_DIM + k0 + kk0);
    dst[0] = *reinterpret_cast<const uint4v*>(&vals[0]);
    dst[1] = *reinterpret_cast<const uint4v*>(&vals[8]);
}

// ---------------------------------------------------------------------------
// Kernel 3: bf16 GEMM, m97 structure. C[rows,N] = A[rows,K] * BT[N,K]^T + bias.
// 128x128 tile, BK=64, 4 waves (2x2), 16x16x32 MFMA, acc[4][4] per wave.
// global_load_lds width=16, linear LDS (lane-linear dest), 2 barriers/K-step.
// Bijective XCD swizzle (m204) -- grid may not be divisible by 8.
// ---------------------------------------------------------------------------
__global__ void gemm_kernel(const unsigned short* __restrict__ A,
                            const unsigned short* __restrict__ BT,
                            const float* __restrict__ bias,
                            float* __restrict__ C) {
    __shared__ unsigned short As[128 * 64];
    __shared__ unsigned short Bs[128 * 64];

    constexpr int NTILES = N_DIM / 128;  // 86
    int wg = blockIdx.x;
    int nwg = gridDim.x;
    // bijective XCD-aware swizzle (works for any nwg)
    int q = nwg >> 3, r = nwg & 7;
    int xcd = wg & 7, li = wg >> 3;
    int swz = (xcd < r ? xcd * (q + 1) : r * (q + 1) + (xcd - r) * q) + li;
    int by = swz / NTILES;
    int bx = swz - by * NTILES;
    int brow = by << 7, bcol = bx << 7;

    int t = threadIdx.x;
    int lane = t & 63;
    int wid = t >> 6;
    int wr = wid >> 1, wc = wid & 1;
    int fr = lane & 15, fq = lane >> 4;

    f32x4 acc[4][4];
#pragma unroll
    for (int m = 0; m < 4; ++m)
#pragma unroll
        for (int n = 0; n < 4; ++n) acc[m][n] = (f32x4){0.f, 0.f, 0.f, 0.f};

    // staging: thread t, issue i covers LDS bytes i*4096 + t*16 (lane-linear)
    int srow = t >> 3;
    int scol = (t & 7) << 3;
    const unsigned short* aSrc = A + (int64_t)(brow + srow) * K_DIM + scol;
    const unsigned short* bSrc = BT + (int64_t)(bcol + srow) * K_DIM + scol;
    unsigned short* aDst = As + srow * 64 + scol;
    unsigned short* bDst = Bs + srow * 64 + scol;

    const unsigned short* aRd = As + (wr * 64 + fr) * 64 + fq * 8;
    const unsigned short* bRd = Bs + (wc * 64 + fr) * 64 + fq * 8;

    for (int kt = 0; kt < K_DIM / 64; ++kt) {
        __syncthreads();   // previous compute done before overwrite
#pragma unroll
        for (int i = 0; i < 4; ++i) {
            gload_lds16(aSrc + i * 32 * K_DIM, aDst + i * 32 * 64);
            gload_lds16(bSrc + i * 32 * K_DIM, bDst + i * 32 * 64);
        }
        __syncthreads();   // compiler drains vmcnt(0) before barrier
#pragma unroll
        for (int kk = 0; kk < 2; ++kk) {
            bf16x8 av[4], bv[4];
#pragma unroll
            for (int m = 0; m < 4; ++m)
                av[m] = *reinterpret_cast<const bf16x8*>(aRd + m * 16 * 64 + kk * 32);
#pragma unroll
            for (int n = 0; n < 4; ++n)
                bv[n] = *reinterpret_cast<const bf16x8*>(bRd + n * 16 * 64 + kk * 32);
#pragma unroll
            for (int m = 0; m < 4; ++m)
#pragma unroll
                for (int n = 0; n < 4; ++n)
                    acc[m][n] = __builtin_amdgcn_mfma_f32_16x16x32_bf16(
                        av[m], bv[n], acc[m][n], 0, 0, 0);
        }
        aSrc += 64;
        bSrc += 64;
    }

    // epilogue: C/D layout col=lane&15, row=(lane>>4)*4+reg
    int orow0 = brow + wr * 64 + fq * 4;
    int ocol0 = bcol + wc * 64 + fr;
#pragma unroll
    for (int n = 0; n < 4; ++n) {
        int col = ocol0 + n * 16;
        float bval = bias[col];
#pragma unroll
        for (int m = 0; m < 4; ++m) {
            int row = orow0 + m * 16;
            float* cp = C + (int64_t)row * N_DIM + col;
#pragma unroll
            for (int j = 0; j < 4; ++j) {
                cp[(int64_t)j * N_DIM] = acc[m][n][j] + bval;
            }
        }
    }
}

extern "C" void kernel_launch(void* const* d_in, const int* in_sizes, int n_in,
                              void* d_out, int out_size, void* d_ws, size_t ws_size,
                              hipStream_t stream) {
    const float* x      = (const float*)d_in[0];
    const int* ci       = (const int*)d_in[1];
    const int* wp       = (const int*)d_in[2];
    const float* scales = (const float*)d_in[3];
    const float* bias   = (const float*)d_in[4];
    float* out          = (float*)d_out;

    // workspace layout: wT bf16 [N,K] (86 MiB) first, then xg chunk.
    // Chunk M so that wT + xg_chunk fits in ws_size (round-1 failure was an
    // OOB write past d_ws corrupting an input across graph replays).
    const size_t wT_bytes = (size_t)N_DIM * K_DIM * 2;  // 90,177,536
    unsigned short* wT = (unsigned short*)d_ws;
    unsigned short* xg = wT + (size_t)N_DIM * K_DIM;

    size_t cap = (ws_size > wT_bytes) ? (ws_size - wT_bytes) : 0;
    int max_rows = (int)(cap / ((size_t)K_DIM * 2));
    int chunk_rows = (max_rows / 128) * 128;
    if (chunk_rows <= 0) chunk_rows = 128;      // best effort
    if (chunk_rows > M_DIM) chunk_rows = M_DIM;

    dequant_w_kernel<<<dim3(N_DIM / 64, K_DIM / 64), 256, 0, stream>>>(wp, scales, wT);

    for (int m0 = 0; m0 < M_DIM; m0 += chunk_rows) {
        int rows = M_DIM - m0 < chunk_rows ? M_DIM - m0 : chunk_rows;
        int pgrid = (int)(((int64_t)rows * K_DIM) / (4 * 256));
        permute_x_kernel<<<pgrid, 256, 0, stream>>>(
            x + (int64_t)m0 * K_DIM, ci, xg);
        int grid = (rows / 128) * (N_DIM / 128);
        gemm_kernel<<<grid, 256, 0, stream>>>(
            xg, wT, bias, out + (int64_t)m0 * N_DIM);
    }
}

// Round 3
// 901.985 us; speedup vs baseline: 1.1089x; 1.1089x over previous
//
#include <hip/hip_runtime.h>
#include <hip/hip_bf16.h>
#include <stdint.h>

#define M_DIM 8192
#define K_DIM 4096
#define N_DIM 11008
#define NKT   (K_DIM / 64)   // 64 K-tiles of 64
#define NIT   (NKT / 2)      // 32 iterations, 2 K-tiles each

typedef __attribute__((ext_vector_type(8))) short bf16x8;
typedef __attribute__((ext_vector_type(4))) float f32x4;
typedef __attribute__((ext_vector_type(4))) unsigned int uint4v;

__device__ __forceinline__ unsigned short f2bf(float f) {
    __hip_bfloat16 h = __float2bfloat16(f);
    return __builtin_bit_cast(unsigned short, h);
}

__device__ __forceinline__ void gload_lds16(const unsigned short* g, unsigned short* l) {
    __builtin_amdgcn_global_load_lds(
        (const __attribute__((address_space(1))) void*)g,
        (__attribute__((address_space(3))) void*)l,
        16, 0, 0);
}

// ---------------------------------------------------------------------------
// Kernel 1: fused column-gather + fp32->bf16 convert for a chunk of M rows.
// ---------------------------------------------------------------------------
__global__ void permute_x_kernel(const float* __restrict__ x,
                                 const int* __restrict__ ci,
                                 unsigned short* __restrict__ xg) {
    int idx = blockIdx.x * 256 + threadIdx.x;
    int64_t base = (int64_t)idx * 4;
    int m = (int)(base >> 12);        // K=4096
    int k = (int)(base & 4095);
    const float* xrow = x + ((int64_t)m << 12);
    int4 c4 = *reinterpret_cast<const int4*>(ci + k);
    ushort4 o;
    o.x = f2bf(xrow[c4.x]);
    o.y = f2bf(xrow[c4.y]);
    o.z = f2bf(xrow[c4.z]);
    o.w = f2bf(xrow[c4.w]);
    *reinterpret_cast<ushort4*>(xg + base) = o;
}

// ---------------------------------------------------------------------------
// Kernel 2: int4 unpack + per-group scale + transpose to wT[N][K] bf16.
// ---------------------------------------------------------------------------
__global__ void dequant_w_kernel(const int* __restrict__ wp,
                                 const float* __restrict__ scales,
                                 unsigned short* __restrict__ wT) {
    __shared__ unsigned short tile[64][65];
    int n0 = blockIdx.x * 64;
    int k0 = blockIdx.y * 64;
    int g = k0 >> 7;
    int t = threadIdx.x;
    int col = t & 63;
    int r0 = t >> 6;
    float s = scales[(int64_t)g * N_DIM + n0 + col];
    int pr0 = k0 >> 1;
#pragma unroll
    for (int i = 0; i < 8; ++i) {
        int row = r0 + i * 4;
        int p = wp[(int64_t)(pr0 + row) * N_DIM + n0 + col];
        tile[2 * row][col]     = f2bf((float)((p & 15) - 8) * s);
        tile[2 * row + 1][col] = f2bf((float)(((p >> 4) & 15) - 8) * s);
    }
    __syncthreads();
    int nl = t >> 2;
    int kk0 = (t & 3) << 4;
    unsigned short vals[16];
#pragma unroll
    for (int j = 0; j < 16; ++j) vals[j] = tile[kk0 + j][nl];
    uint4v* dst = reinterpret_cast<uint4v*>(wT + (int64_t)(n0 + nl) * K_DIM + k0 + kk0);
    dst[0] = *reinterpret_cast<const uint4v*>(&vals[0]);
    dst[1] = *reinterpret_cast<const uint4v*>(&vals[8]);
}

// ---------------------------------------------------------------------------
// Kernel 3: bf16 GEMM, 256x256 tile, 8-phase schedule (T3+T4+T5).
// LDS 128 KiB = 2 buffers x {A_k0, A_k1, B_k0, B_k1}, each region
// [256 rows][32 k] bf16 (16 KiB, 64B rows -> conflict-free b128 frag reads).
// Element offsets (ushort): buf*32768 + isB*16384 + kk*8192.
//
// Phase table (iteration it; tiles T0=2it in buf0, T1=2it+1 in buf1):
//  ph1: read buf0.A_k0 m0-3 + buf0.B_k0      | stage buf1.A_k1 <- 2it+1
//  ph2: read buf0.A_k0 m4-7 + buf0.A_k1 m0-3 | stage buf0.B_k0 <- 2it+2
//  ph3: read buf0.A_k1 m4-7 + buf0.B_k1      | stage buf0.A_k0 <- 2it+2
//  ph4: (no reads)                           | stage buf0.B_k1 <- 2it+2 | vmcnt(6)
//  ph5: read buf1.A_k0 m0-3 + buf1.B_k0      | stage buf0.A_k1 <- 2it+2
//  ph6: read buf1.A_k0 m4-7 + buf1.A_k1 m0-3 | stage buf1.B_k0 <- 2it+3
//  ph7: read buf1.A_k1 m4-7 + buf1.B_k1      | stage buf1.A_k0 <- 2it+3
//  ph8: (no reads)                           | stage buf1.B_k1 <- 2it+3 | vmcnt(6)
// Every region's overwrite is issued >=1 barrier after its last data return;
// vmcnt(6) at ph4/ph8 guarantees the next K-tile's 4 regions have landed.
// ---------------------------------------------------------------------------

template <int BUF, int KK, int MB>
__device__ __forceinline__ void lda4(bf16x8 (&d)[8], const unsigned short* lds, int aBase) {
#pragma unroll
    for (int m = 0; m < 4; ++m)
        d[MB + m] = *reinterpret_cast<const bf16x8*>(
            lds + BUF * 32768 + KK * 8192 + aBase + (MB + m) * 512);
}

template <int BUF, int KK>
__device__ __forceinline__ void ldb4(bf16x8 (&d)[4], const unsigned short* lds, int bBase) {
#pragma unroll
    for (int n = 0; n < 4; ++n)
        d[n] = *reinterpret_cast<const bf16x8*>(
            lds + BUF * 32768 + 16384 + KK * 8192 + bBase + n * 512);
}

template <int MB>
__device__ __forceinline__ void mfma_blk(f32x4 (&acc)[8][4], const bf16x8 (&av)[8],
                                         const bf16x8 (&bv)[4]) {
    __builtin_amdgcn_s_setprio(1);
#pragma unroll
    for (int m = 0; m < 4; ++m)
#pragma unroll
        for (int n = 0; n < 4; ++n)
            acc[MB + m][n] = __builtin_amdgcn_mfma_f32_16x16x32_bf16(
                av[MB + m], bv[n], acc[MB + m][n], 0, 0, 0);
    __builtin_amdgcn_s_setprio(0);
}

// stage one 16 KiB region (256 rows x 32 k) of tile kt: 2 gload_lds per wave.
template <int BUF, int ISB, int KK>
__device__ __forceinline__ void stage(const unsigned short* __restrict__ G, int row0,
                                      int kt, unsigned short* lds,
                                      int w32, int riw, int s8, int wLds) {
    if (kt < NKT) {
#pragma unroll
        for (int j = 0; j < 2; ++j) {
            const unsigned short* src =
                G + (int64_t)(row0 + w32 + j * 16 + riw) * K_DIM + kt * 64 + KK * 32 + s8;
            gload_lds16(src, lds + BUF * 32768 + ISB * 16384 + KK * 8192 + wLds + j * 512);
        }
    }
}

#define BAR() do { __builtin_amdgcn_s_barrier(); asm volatile("" ::: "memory"); } while (0)

__global__ __launch_bounds__(512, 2)
void gemm_kernel(const unsigned short* __restrict__ A,
                 const unsigned short* __restrict__ BT,
                 const float* __restrict__ bias,
                 float* __restrict__ C) {
    __shared__ unsigned short lds[65536];   // 128 KiB

    constexpr int NT = N_DIM / 256;  // 43
    int wg = blockIdx.x, nwg = gridDim.x;
    int q = nwg >> 3, r = nwg & 7;
    int xcd = wg & 7, li = wg >> 3;
    int swz = (xcd < r ? xcd * (q + 1) : r * (q + 1) + (xcd - r) * q) + li;
    int by = swz / NT, bx = swz - by * NT;
    int brow = by << 8, bcol = bx << 8;

    int t = threadIdx.x;
    int lane = t & 63, w = t >> 6;
    int wr = w >> 2, wc = w & 3;           // 2 x 4 wave grid
    int fr = lane & 15, fq = lane >> 4;

    const int aBase = (wr * 128 + fr) * 32 + fq * 8;
    const int bBase = (wc * 64 + fr) * 32 + fq * 8;
    const int riw = lane >> 2, s8 = (lane & 3) << 3;
    const int w32 = w * 32, wLds = w * 1024;

    f32x4 acc[8][4];
#pragma unroll
    for (int m = 0; m < 8; ++m)
#pragma unroll
        for (int n = 0; n < 4; ++n) acc[m][n] = (f32x4){0.f, 0.f, 0.f, 0.f};

    // ---- prologue: buf0 <- tile0 (all 4 regions, 8 loads), buf1 <- tile1
    // {B_k0, A_k0, B_k1} (6 loads). vmcnt(6) -> buf0 landed.
    stage<0, 0, 0>(A,  brow, 0, lds, w32, riw, s8, wLds);   // buf0.A_k0
    stage<0, 0, 1>(A,  brow, 0, lds, w32, riw, s8, wLds);   // buf0.A_k1
    stage<0, 1, 0>(BT, bcol, 0, lds, w32, riw, s8, wLds);   // buf0.B_k0
    stage<0, 1, 1>(BT, bcol, 0, lds, w32, riw, s8, wLds);   // buf0.B_k1
    stage<1, 1, 0>(BT, bcol, 1, lds, w32, riw, s8, wLds);   // buf1.B_k0
    stage<1, 0, 0>(A,  brow, 1, lds, w32, riw, s8, wLds);   // buf1.A_k0
    stage<1, 1, 1>(BT, bcol, 1, lds, w32, riw, s8, wLds);   // buf1.B_k1
    asm volatile("s_waitcnt vmcnt(6)" ::: "memory");
    BAR();

#pragma unroll 1
    for (int it = 0; it < NIT; ++it) {
        const int t1 = 2 * it + 1, t2 = 2 * it + 2, t3 = 2 * it + 3;
        const bool lastIt = (it == NIT - 1);
        bf16x8 a0[8], a1[8], b0[4], b1[4];

        // ---------------- phase 1 ----------------
        lda4<0, 0, 0>(a0, lds, aBase);
        ldb4<0, 0>(b0, lds, bBase);
        stage<1, 0, 1>(A, brow, t1, lds, w32, riw, s8, wLds);   // buf1.A_k1 <- t1
        BAR();
        mfma_blk<0>(acc, a0, b0);
        BAR();

        // ---------------- phase 2 ----------------
        lda4<0, 0, 4>(a0, lds, aBase);
        lda4<0, 1, 0>(a1, lds, aBase);
        stage<0, 1, 0>(BT, bcol, t2, lds, w32, riw, s8, wLds);  // buf0.B_k0 <- t2
        BAR();
        mfma_blk<4>(acc, a0, b0);
        BAR();

        // ---------------- phase 3 ----------------
        lda4<0, 1, 4>(a1, lds, aBase);
        ldb4<0, 1>(b1, lds, bBase);
        stage<0, 0, 0>(A, brow, t2, lds, w32, riw, s8, wLds);   // buf0.A_k0 <- t2
        BAR();
        mfma_blk<0>(acc, a1, b1);
        BAR();

        // ---------------- phase 4 ----------------
        stage<0, 1, 1>(BT, bcol, t2, lds, w32, riw, s8, wLds);  // buf0.B_k1 <- t2
        BAR();
        mfma_blk<4>(acc, a1, b1);
        if (!lastIt) asm volatile("s_waitcnt vmcnt(6)" ::: "memory");
        else         asm volatile("s_waitcnt vmcnt(0)" ::: "memory");
        BAR();

        // ---------------- phase 5 ----------------
        lda4<1, 0, 0>(a0, lds, aBase);
        ldb4<1, 0>(b0, lds, bBase);
        stage<0, 0, 1>(A, brow, t2, lds, w32, riw, s8, wLds);   // buf0.A_k1 <- t2
        BAR();
        mfma_blk<0>(acc, a0, b0);
        BAR();

        // ---------------- phase 6 ----------------
        lda4<1, 0, 4>(a0, lds, aBase);
        lda4<1, 1, 0>(a1, lds, aBase);
        stage<1, 1, 0>(BT, bcol, t3, lds, w32, riw, s8, wLds);  // buf1.B_k0 <- t3
        BAR();
        mfma_blk<4>(acc, a0, b0);
        BAR();

        // ---------------- phase 7 ----------------
        lda4<1, 1, 4>(a1, lds, aBase);
        ldb4<1, 1>(b1, lds, bBase);
        stage<1, 0, 0>(A, brow, t3, lds, w32, riw, s8, wLds);   // buf1.A_k0 <- t3
        BAR();
        mfma_blk<0>(acc, a1, b1);
        BAR();

        // ---------------- phase 8 ----------------
        stage<1, 1, 1>(BT, bcol, t3, lds, w32, riw, s8, wLds);  // buf1.B_k1 <- t3
        BAR();
        mfma_blk<4>(acc, a1, b1);
        if (!lastIt) asm volatile("s_waitcnt vmcnt(6)" ::: "memory");
        BAR();
    }

    // ---- epilogue: C/D layout col=lane&15, row=(lane>>4)*4+reg ----
    int orow0 = brow + wr * 128 + fq * 4;
    int ocol0 = bcol + wc * 64 + fr;
#pragma unroll
    for (int n = 0; n < 4; ++n) {
        int col = ocol0 + n * 16;
        float bval = bias[col];
#pragma unroll
        for (int m = 0; m < 8; ++m) {
            int row = orow0 + m * 16;
            float* cp = C + (int64_t)row * N_DIM + col;
#pragma unroll
            for (int j = 0; j < 4; ++j) {
                cp[(int64_t)j * N_DIM] = acc[m][n][j] + bval;
            }
        }
    }
}

extern "C" void kernel_launch(void* const* d_in, const int* in_sizes, int n_in,
                              void* d_out, int out_size, void* d_ws, size_t ws_size,
                              hipStream_t stream) {
    const float* x      = (const float*)d_in[0];
    const int* ci       = (const int*)d_in[1];
    const int* wp       = (const int*)d_in[2];
    const float* scales = (const float*)d_in[3];
    const float* bias   = (const float*)d_in[4];
    float* out          = (float*)d_out;

    // workspace: wT bf16 [N,K] (86 MiB) first, then xg chunk (fit to ws_size).
    const size_t wT_bytes = (size_t)N_DIM * K_DIM * 2;
    unsigned short* wT = (unsigned short*)d_ws;
    unsigned short* xg = wT + (size_t)N_DIM * K_DIM;

    size_t cap = (ws_size > wT_bytes) ? (ws_size - wT_bytes) : 0;
    int max_rows = (int)(cap / ((size_t)K_DIM * 2));
    int chunk_rows = (max_rows / 256) * 256;
    if (chunk_rows <= 0) chunk_rows = 256;      // best effort
    if (chunk_rows > M_DIM) chunk_rows = M_DIM;

    dequant_w_kernel<<<dim3(N_DIM / 64, K_DIM / 64), 256, 0, stream>>>(wp, scales, wT);

    for (int m0 = 0; m0 < M_DIM; m0 += chunk_rows) {
        int rows = M_DIM - m0 < chunk_rows ? M_DIM - m0 : chunk_rows;
        int pgrid = (int)(((int64_t)rows * K_DIM) / (4 * 256));
        permute_x_kernel<<<pgrid, 256, 0, stream>>>(
            x + (int64_t)m0 * K_DIM, ci, xg);
        int grid = (rows / 256) * (N_DIM / 256);
        gemm_kernel<<<grid, 512, 0, stream>>>(
            xg, wT, bias, out + (int64_t)m0 * N_DIM);
    }
}